// Round 6
// baseline (270.620 us; speedup 1.0000x reference)
//
#include <hip/hip_runtime.h>
#include <hip/hip_bf16.h>
#include <stdint.h>

#define NTOK 8192
#define DDIM 1024
#define HDIM 512

typedef __attribute__((ext_vector_type(8))) __bf16 bf16x8;
typedef __attribute__((ext_vector_type(4))) float f32x4;
typedef __attribute__((ext_vector_type(2))) uint32_t u32x2;

__device__ __forceinline__ void gload16(const void* g, void* lds) {
  __builtin_amdgcn_global_load_lds(
      (const __attribute__((address_space(1))) void*)g,
      (__attribute__((address_space(3))) void*)lds,
      16, 0, 0);
}

// ---------------- fused X convert + routing (NO global atomics) ----------------

__global__ __launch_bounds__(256)
void convert_route_kernel(const float* __restrict__ X, const float* __restrict__ rW,
                          const float* __restrict__ ebias,
                          __hip_bfloat16* __restrict__ Xb,
                          int* __restrict__ top_e, float* __restrict__ top_w) {
  int wid = threadIdx.x >> 6, lane = threadIdx.x & 63;
  int tok = blockIdx.x * 4 + wid;
  const float4* xr = (const float4*)(X + (size_t)tok * DDIM);
  u32x2* xb = (u32x2*)(Xb + (size_t)tok * DDIM);
  float acc[8];
  #pragma unroll
  for (int e = 0; e < 8; e++) acc[e] = 0.f;
  #pragma unroll
  for (int c = 0; c < 4; c++) {
    int j = c * 64 + lane;
    float4 x = xr[j];
    union { __hip_bfloat16 h[4]; u32x2 u; } cv;
    cv.h[0] = __float2bfloat16(x.x); cv.h[1] = __float2bfloat16(x.y);
    cv.h[2] = __float2bfloat16(x.z); cv.h[3] = __float2bfloat16(x.w);
    xb[j] = cv.u;
    #pragma unroll
    for (int e = 0; e < 8; e++) {
      float4 w = ((const float4*)(rW + (size_t)e * DDIM))[j];
      acc[e] += x.x * w.x + x.y * w.y + x.z * w.z + x.w * w.w;
    }
  }
  #pragma unroll
  for (int m = 1; m < 64; m <<= 1)
    #pragma unroll
    for (int e = 0; e < 8; e++) acc[e] += __shfl_xor(acc[e], m, 64);
  if (lane == 0) {
    float act[8];
    #pragma unroll
    for (int e = 0; e < 8; e++) {
      float x = acc[e] + ebias[e];
      float sp = (x > 15.f) ? x : log1pf(expf(x));
      act[e] = sqrtf(sp);
    }
    int e1 = 0; float v1 = act[0];
    #pragma unroll
    for (int e = 1; e < 8; e++) if (act[e] > v1) { v1 = act[e]; e1 = e; }
    int e2 = -1; float v2 = -1.f;
    #pragma unroll
    for (int e = 0; e < 8; e++) if (e != e1 && act[e] > v2) { v2 = act[e]; e2 = e; }
    top_e[tok * 2] = e1; top_e[tok * 2 + 1] = e2;
    top_w[tok * 2] = v1; top_w[tok * 2 + 1] = v2;
  }
}

// fused W1-family / W2-family transpose+convert: z=0 -> shared, z>=1 -> expert z-1
__global__ void convert_w_kernel(const float* __restrict__ sIn, const float* __restrict__ rIn,
                                 __hip_bfloat16* __restrict__ sOut, __hip_bfloat16* __restrict__ rOut,
                                 int K, int Nn) {
  __shared__ float tile[32][33];
  int z = blockIdx.z;
  const float* src = (z == 0) ? sIn : rIn + (size_t)(z - 1) * K * Nn;
  __hip_bfloat16* dst = (z == 0) ? sOut : rOut + (size_t)(z - 1) * K * Nn;
  int n0 = blockIdx.x * 32, k0 = blockIdx.y * 32;
  int c = threadIdx.x & 31, r = threadIdx.x >> 5;
  #pragma unroll
  for (int i = 0; i < 4; i++)
    tile[r + i * 8][c] = src[(size_t)(k0 + r + i * 8) * Nn + n0 + c];
  __syncthreads();
  #pragma unroll
  for (int i = 0; i < 4; i++)
    dst[(size_t)(n0 + r + i * 8) * K + k0 + c] = __float2bfloat16(tile[c][r + i * 8]);
}

// ---------------- hist + scan fused (one block, no global atomics) ----------------

__global__ __launch_bounds__(512)
void hist_scan_kernel(const int* __restrict__ top_e, int* __restrict__ chunkBase,
                      int* __restrict__ counts, int* __restrict__ offs,
                      int* __restrict__ tiles) {
  __shared__ int hist[64][8];
  __shared__ int cnt_s[8];
  __shared__ int offs_s[8];
  int i = threadIdx.x;  // 512
  int c = i >> 3, e = i & 7;
  const int* p = top_e + c * 256;
  int n = 0;
  for (int j = 0; j < 256; j++) n += (p[j] == e) ? 1 : 0;
  hist[c][e] = n;
  __syncthreads();
  if (i < 8) {
    int run = 0;
    for (int b = 0; b < 64; b++) { int t = hist[b][i]; hist[b][i] = run; run += t; }
    cnt_s[i] = run;
    counts[i] = run;
  }
  __syncthreads();
  if (i == 0) {
    int s = 0, tb = 0;
    for (int k = 0; k < 8; k++) {
      offs_s[k] = s; offs[k] = s; s += cnt_s[k];
      tiles[k] = tb; tb += (cnt_s[k] + 127) >> 7;
    }
    offs[8] = s;
    tiles[8] = tb;
  }
  __syncthreads();
  chunkBase[c * 8 + e] = hist[c][e] + offs_s[e];
}

__global__ void scatter_kernel(const int* __restrict__ top_e, const float* __restrict__ top_w,
                               const int* __restrict__ chunkBase,
                               int* __restrict__ list, float* __restrict__ wlist,
                               int* __restrict__ inv) {
  __shared__ int lcnt[8];
  if (threadIdx.x < 8) lcnt[threadIdx.x] = 0;
  __syncthreads();
  int a = blockIdx.x * 256 + threadIdx.x;
  int e = top_e[a];
  int p = atomicAdd(&lcnt[e], 1);
  int pos = chunkBase[blockIdx.x * 8 + e] + p;
  list[pos] = a >> 1;
  wlist[pos] = top_w[a];
  inv[a] = pos;
}

// ---------------- GEMM: 128x128 tile, BK=32, 2-phase dbuf, full LDS swizzle ----
// MODE 1: H = silu(X@W1+b1); logical [0,256) shared, [256,..) routed gather
// MODE 3: ybuf[pos] = w*(Hr@rW2+rb2)  (bf16 slot store, routed only)
// MODE 2: out = Hs@sW2+sb2 + y[slot0] + y[slot1]  (shared + fused combine)
//
// LDS chunk swizzle sigma: (r,k) -> (r ^ ((r>>2)&1), k ^ (r&3)); involution on
// rows, spreads 8 consecutive rows across all 8 bank groups (2-way = free).

template<int MODE>
__global__ __launch_bounds__(256, 4)
void gemm_kernel(const __hip_bfloat16* __restrict__ Abase,
                 const __hip_bfloat16* __restrict__ Ws,
                 const __hip_bfloat16* __restrict__ Wr,
                 const float* __restrict__ bs,
                 const float* __restrict__ br,
                 __hip_bfloat16* __restrict__ Hout,
                 float* __restrict__ Oout,
                 __hip_bfloat16* __restrict__ Ybuf,
                 const int* __restrict__ counts,
                 const int* __restrict__ offs,
                 const int* __restrict__ tiles,
                 const int* __restrict__ list,
                 const float* __restrict__ wlist,
                 const int* __restrict__ inv) {
  constexpr int K    = (MODE == 1) ? 1024 : 512;
  constexpr int NN   = (MODE == 1) ? 512 : 1024;
  constexpr int LDBy = K * 2;
  constexpr int LNT  = (MODE == 1) ? 2 : 3;   // log2(n-tiles)
  constexpr int NT   = K / 32;

  __shared__ __hip_bfloat16 Abuf[2][128 * 32];
  __shared__ __hip_bfloat16 Bbuf[2][128 * 32];
  __shared__ int tokens[128];

  // bijective XCD-chunked swizzle (grid % 8 == 0)
  int l = ((blockIdx.x & 7) * (gridDim.x >> 3)) + (blockIdx.x >> 3);

  int e = 0, mt, nt;
  bool rb = false;
  if (MODE == 2) { mt = l >> 3; nt = l & 7; }
  else if (MODE == 1 && l < 256) { mt = l >> 2; nt = l & 3; }
  else {
    rb = true;
    int rq = (MODE == 1) ? (l - 256) : l;
    int rt = rq >> LNT; nt = rq & ((1 << LNT) - 1);
    if (rt >= tiles[8]) return;
    while (e < 7 && rt >= tiles[e + 1]) ++e;
    mt = rt - tiles[e];
  }
  int m0 = mt * 128;
  int cnt = 128;
  if (rb) {
    int ce = counts[e];
    cnt = (ce - m0 < 128) ? (ce - m0) : 128;
  }

  const __hip_bfloat16* W = rb ? (Wr + (size_t)e * NN * K) : Ws;
  const float* bias = rb ? (br + e * NN) : bs;

  int tid = threadIdx.x, wid = tid >> 6, lane = tid & 63;
  if (MODE == 1) {
    if (tid < 128)
      tokens[tid] = rb ? ((tid < cnt) ? list[offs[e] + m0 + tid] : 0) : (m0 + tid);
    __syncthreads();
  }
  int arow0 = rb ? (NTOK + offs[e] + m0) : m0;  // MODE 2/3

  // staging: LDS written linearly by gload_lds; global source pre-inverse-swizzled
  const char* aSrc[2];
  const char* bSrc[2];
  int ldsOff[2];
  #pragma unroll
  for (int c = 0; c < 2; c++) {
    ldsOff[c] = c * 4096 + wid * 1024;           // wave-uniform LDS base
    int s = ldsOff[c] + lane * 16;               // this lane's linear LDS byte
    int rho = s >> 6;                            // linear LDS row
    int klin = (s >> 4) & 3;
    int r = rho ^ ((rho >> 2) & 1);              // sigma^-1 row (involution)
    int k = klin ^ (r & 3);                      // sigma^-1 chunk
    long ar = (MODE == 1) ? (long)tokens[r] : (long)(arow0 + r);
    aSrc[c] = (const char*)Abase + (size_t)ar * LDBy + k * 16;
    bSrc[c] = (const char*)W + (size_t)(nt * 128 + r) * LDBy + k * 16;
  }

  int wm = wid >> 1, wn = wid & 1;
  int aoff[4], boff[4];
  #pragma unroll
  for (int m = 0; m < 4; m++) {
    int row = wm * 64 + m * 16 + (lane & 15);
    int rr = row ^ ((row >> 2) & 1);
    int kk = (lane >> 4) ^ (row & 3);
    aoff[m] = rr * 64 + kk * 16;
  }
  #pragma unroll
  for (int n = 0; n < 4; n++) {
    int row = wn * 64 + n * 16 + (lane & 15);
    int rr = row ^ ((row >> 2) & 1);
    int kk = (lane >> 4) ^ (row & 3);
    boff[n] = rr * 64 + kk * 16;
  }

  f32x4 zero = {0.f, 0.f, 0.f, 0.f};
  f32x4 acc[4][4];
  #pragma unroll
  for (int m = 0; m < 4; m++)
    #pragma unroll
    for (int n = 0; n < 4; n++) acc[m][n] = zero;

  auto stage = [&](int buf, int kt) {
    #pragma unroll
    for (int c = 0; c < 2; c++)
      gload16(aSrc[c] + (size_t)kt * 64, (char*)&Abuf[0][0] + buf * 8192 + ldsOff[c]);
    #pragma unroll
    for (int c = 0; c < 2; c++)
      gload16(bSrc[c] + (size_t)kt * 64, (char*)&Bbuf[0][0] + buf * 8192 + ldsOff[c]);
  };

  // 2-phase pipeline: stage(next) issued BEFORE compute; the single
  // __syncthreads (implicit vmcnt(0)) lands AFTER MFMA -> latency hidden.
  stage(0, 0);
  __syncthreads();
  int cur = 0;
  for (int kt = 0; kt < NT; ++kt) {
    if (kt + 1 < NT) stage(cur ^ 1, kt + 1);
    const char* lA = (const char*)&Abuf[0][0] + cur * 8192;
    const char* lB = (const char*)&Bbuf[0][0] + cur * 8192;
    bf16x8 a[4], b[4];
    #pragma unroll
    for (int m = 0; m < 4; m++) a[m] = *(const bf16x8*)(lA + aoff[m]);
    #pragma unroll
    for (int n = 0; n < 4; n++) b[n] = *(const bf16x8*)(lB + boff[n]);
    #pragma unroll
    for (int m = 0; m < 4; m++)
      #pragma unroll
      for (int n = 0; n < 4; n++)
        acc[m][n] = __builtin_amdgcn_mfma_f32_16x16x32_bf16(a[m], b[n], acc[m][n], 0, 0, 0);
    __syncthreads();
    cur ^= 1;
  }

  int colBase = nt * 128 + wn * 64;
  if (MODE == 1) {
    size_t hrow0 = rb ? (size_t)(NTOK + offs[e] + m0) : (size_t)m0;
    #pragma unroll
    for (int m = 0; m < 4; m++) {
      #pragma unroll
      for (int r = 0; r < 4; r++) {
        int rl = wm * 64 + m * 16 + ((lane >> 4) << 2) + r;
        if (rl < cnt) {
          #pragma unroll
          for (int n = 0; n < 4; n++) {
            int col = colBase + n * 16 + (lane & 15);
            float v = acc[m][n][r] + bias[col];
            v = v / (1.f + __expf(-v));  // silu
            Hout[(hrow0 + rl) * HDIM + col] = __float2bfloat16(v);
          }
        }
      }
    }
  } else if (MODE == 2) {
    #pragma unroll
    for (int m = 0; m < 4; m++) {
      #pragma unroll
      for (int r = 0; r < 4; r++) {
        int rl = wm * 64 + m * 16 + ((lane >> 4) << 2) + r;
        int t = m0 + rl;
        int p0 = inv[t * 2], p1 = inv[t * 2 + 1];
        #pragma unroll
        for (int n = 0; n < 4; n++) {
          int col = colBase + n * 16 + (lane & 15);
          float v = acc[m][n][r] + bias[col]
                  + __bfloat162float(Ybuf[(size_t)p0 * DDIM + col])
                  + __bfloat162float(Ybuf[(size_t)p1 * DDIM + col]);
          Oout[(size_t)t * DDIM + col] = v;
        }
      }
    }
  } else {
    #pragma unroll
    for (int m = 0; m < 4; m++) {
      #pragma unroll
      for (int r = 0; r < 4; r++) {
        int rl = wm * 64 + m * 16 + ((lane >> 4) << 2) + r;
        if (rl < cnt) {
          int pos = offs[e] + m0 + rl;
          float w = wlist[pos];
          #pragma unroll
          for (int n = 0; n < 4; n++) {
            int col = colBase + n * 16 + (lane & 15);
            Ybuf[(size_t)pos * DDIM + col] = __float2bfloat16(w * (acc[m][n][r] + bias[col]));
          }
        }
      }
    }
  }
}

// ---------------- launch ----------------

extern "C" void kernel_launch(void* const* d_in, const int* in_sizes, int n_in,
                              void* d_out, int out_size, void* d_ws, size_t ws_size,
                              hipStream_t stream) {
  const float* X   = (const float*)d_in[0];
  const float* rWt = (const float*)d_in[1];
  const float* eb  = (const float*)d_in[2];
  const float* sW1 = (const float*)d_in[3];
  const float* sb1 = (const float*)d_in[4];
  const float* sW2 = (const float*)d_in[5];
  const float* sb2 = (const float*)d_in[6];
  const float* rW1 = (const float*)d_in[7];
  const float* rb1 = (const float*)d_in[8];
  const float* rW2 = (const float*)d_in[9];
  const float* rb2 = (const float*)d_in[10];
  float* out = (float*)d_out;

  char* ws = (char*)d_ws;
  size_t off = 0;
  auto alloc = [&](size_t bytes) {
    char* p = ws + off;
    off += (bytes + 255) & ~(size_t)255;
    return p;
  };
  // Region 0 (32 MB): {Xb, sW1t, rW1t} live through gemm<1>; aliased afterward
  // by Ybuf (16384 x 1024 bf16), written by gemm<3>, read by gemm<2> epilogue.
  char* region0 = alloc((size_t)16384 * DDIM * 2);
  __hip_bfloat16* Xb   = (__hip_bfloat16*)region0;
  __hip_bfloat16* sW1t = (__hip_bfloat16*)(region0 + (size_t)NTOK * DDIM * 2);
  __hip_bfloat16* rW1t = (__hip_bfloat16*)(region0 + (size_t)NTOK * DDIM * 2
                                                   + (size_t)HDIM * DDIM * 2);
  __hip_bfloat16* Ybuf = (__hip_bfloat16*)region0;

  __hip_bfloat16* sW2t = (__hip_bfloat16*)alloc((size_t)DDIM * HDIM * 2);
  __hip_bfloat16* rW2t = (__hip_bfloat16*)alloc((size_t)8 * DDIM * HDIM * 2);
  __hip_bfloat16* Hbuf = (__hip_bfloat16*)alloc((size_t)(NTOK + 2 * NTOK) * HDIM * 2);
  alloc(131072);  // pad: partial-tile A reads may run past Hbuf end
  int* counts    = (int*)alloc(64);
  int* offsA     = (int*)alloc(64);
  int* tiles     = (int*)alloc(64);
  int* top_e     = (int*)alloc((size_t)NTOK * 2 * 4);
  float* top_w   = (float*)alloc((size_t)NTOK * 2 * 4);
  int* list      = (int*)alloc((size_t)NTOK * 2 * 4);
  float* wlist   = (float*)alloc((size_t)NTOK * 2 * 4);
  int* inv       = (int*)alloc((size_t)NTOK * 2 * 4);
  int* chunkBase = (int*)alloc(64 * 8 * 4);

  convert_route_kernel<<<2048, 256, 0, stream>>>(X, rWt, eb, Xb, top_e, top_w);
  convert_w_kernel<<<dim3(16, 32, 9), 256, 0, stream>>>(sW1, rW1, sW1t, rW1t, 1024, 512);
  convert_w_kernel<<<dim3(32, 16, 9), 256, 0, stream>>>(sW2, rW2, sW2t, rW2t, 512, 1024);
  hist_scan_kernel<<<1, 512, 0, stream>>>(top_e, chunkBase, counts, offsA, tiles);
  scatter_kernel<<<64, 256, 0, stream>>>(top_e, top_w, chunkBase, list, wlist, inv);
  // grids all % 8 == 0 for the XCD swizzle
  gemm_kernel<1><<<256 + 4 * 136, 256, 0, stream>>>(Xb, sW1t, rW1t, sb1, rb1, Hbuf, out,
                                                    nullptr, counts, offsA, tiles, list, wlist, inv);
  gemm_kernel<3><<<8 * 136, 256, 0, stream>>>(Hbuf, sW2t, rW2t, sb2, rb2, nullptr, out,
                                              Ybuf, counts, offsA, tiles, list, wlist, inv);
  gemm_kernel<2><<<64 * 8, 256, 0, stream>>>(Hbuf, sW2t, rW2t, sb2, rb2, nullptr, out,
                                             Ybuf, counts, offsA, tiles, list, wlist, inv);
}

// Round 7
// 267.743 us; speedup vs baseline: 1.0107x; 1.0107x over previous
//
#include <hip/hip_runtime.h>
#include <hip/hip_bf16.h>
#include <stdint.h>

#define NTOK 8192
#define DDIM 1024
#define HDIM 512

typedef __attribute__((ext_vector_type(8))) __bf16 bf16x8;
typedef __attribute__((ext_vector_type(4))) float f32x4;
typedef __attribute__((ext_vector_type(2))) uint32_t u32x2;

__device__ __forceinline__ void gload16(const void* g, void* lds) {
  __builtin_amdgcn_global_load_lds(
      (const __attribute__((address_space(1))) void*)g,
      (__attribute__((address_space(3))) void*)lds,
      16, 0, 0);
}

// ---------------- fused X convert + routing (NO global atomics) ----------------

__global__ __launch_bounds__(256)
void convert_route_kernel(const float* __restrict__ X, const float* __restrict__ rW,
                          const float* __restrict__ ebias,
                          __hip_bfloat16* __restrict__ Xb,
                          int* __restrict__ top_e, float* __restrict__ top_w) {
  int wid = threadIdx.x >> 6, lane = threadIdx.x & 63;
  int tok = blockIdx.x * 4 + wid;
  const float4* xr = (const float4*)(X + (size_t)tok * DDIM);
  u32x2* xb = (u32x2*)(Xb + (size_t)tok * DDIM);
  float acc[8];
  #pragma unroll
  for (int e = 0; e < 8; e++) acc[e] = 0.f;
  #pragma unroll
  for (int c = 0; c < 4; c++) {
    int j = c * 64 + lane;
    float4 x = xr[j];
    union { __hip_bfloat16 h[4]; u32x2 u; } cv;
    cv.h[0] = __float2bfloat16(x.x); cv.h[1] = __float2bfloat16(x.y);
    cv.h[2] = __float2bfloat16(x.z); cv.h[3] = __float2bfloat16(x.w);
    xb[j] = cv.u;
    #pragma unroll
    for (int e = 0; e < 8; e++) {
      float4 w = ((const float4*)(rW + (size_t)e * DDIM))[j];
      acc[e] += x.x * w.x + x.y * w.y + x.z * w.z + x.w * w.w;
    }
  }
  #pragma unroll
  for (int m = 1; m < 64; m <<= 1)
    #pragma unroll
    for (int e = 0; e < 8; e++) acc[e] += __shfl_xor(acc[e], m, 64);
  if (lane == 0) {
    float act[8];
    #pragma unroll
    for (int e = 0; e < 8; e++) {
      float x = acc[e] + ebias[e];
      float sp = (x > 15.f) ? x : log1pf(expf(x));
      act[e] = sqrtf(sp);
    }
    int e1 = 0; float v1 = act[0];
    #pragma unroll
    for (int e = 1; e < 8; e++) if (act[e] > v1) { v1 = act[e]; e1 = e; }
    int e2 = -1; float v2 = -1.f;
    #pragma unroll
    for (int e = 0; e < 8; e++) if (e != e1 && act[e] > v2) { v2 = act[e]; e2 = e; }
    top_e[tok * 2] = e1; top_e[tok * 2 + 1] = e2;
    top_w[tok * 2] = v1; top_w[tok * 2 + 1] = v2;
  }
}

// fused W1-family / W2-family transpose+convert: z=0 -> shared, z>=1 -> expert z-1
__global__ void convert_w_kernel(const float* __restrict__ sIn, const float* __restrict__ rIn,
                                 __hip_bfloat16* __restrict__ sOut, __hip_bfloat16* __restrict__ rOut,
                                 int K, int Nn) {
  __shared__ float tile[32][33];
  int z = blockIdx.z;
  const float* src = (z == 0) ? sIn : rIn + (size_t)(z - 1) * K * Nn;
  __hip_bfloat16* dst = (z == 0) ? sOut : rOut + (size_t)(z - 1) * K * Nn;
  int n0 = blockIdx.x * 32, k0 = blockIdx.y * 32;
  int c = threadIdx.x & 31, r = threadIdx.x >> 5;
  #pragma unroll
  for (int i = 0; i < 4; i++)
    tile[r + i * 8][c] = src[(size_t)(k0 + r + i * 8) * Nn + n0 + c];
  __syncthreads();
  #pragma unroll
  for (int i = 0; i < 4; i++)
    dst[(size_t)(n0 + r + i * 8) * K + k0 + c] = __float2bfloat16(tile[c][r + i * 8]);
}

// ---------------- hist + scan fused (one block, no global atomics) ----------------

__global__ __launch_bounds__(512)
void hist_scan_kernel(const int* __restrict__ top_e, int* __restrict__ chunkBase,
                      int* __restrict__ counts, int* __restrict__ offs,
                      int* __restrict__ tiles) {
  __shared__ int hist[64][8];
  __shared__ int cnt_s[8];
  __shared__ int offs_s[8];
  int i = threadIdx.x;  // 512
  int c = i >> 3, e = i & 7;
  const int* p = top_e + c * 256;
  int n = 0;
  for (int j = 0; j < 256; j++) n += (p[j] == e) ? 1 : 0;
  hist[c][e] = n;
  __syncthreads();
  if (i < 8) {
    int run = 0;
    for (int b = 0; b < 64; b++) { int t = hist[b][i]; hist[b][i] = run; run += t; }
    cnt_s[i] = run;
    counts[i] = run;
  }
  __syncthreads();
  if (i == 0) {
    int s = 0, tb = 0;
    for (int k = 0; k < 8; k++) {
      offs_s[k] = s; offs[k] = s; s += cnt_s[k];
      tiles[k] = tb; tb += (cnt_s[k] + 127) >> 7;
    }
    offs[8] = s;
    tiles[8] = tb;
  }
  __syncthreads();
  chunkBase[c * 8 + e] = hist[c][e] + offs_s[e];
}

__global__ void scatter_kernel(const int* __restrict__ top_e, const float* __restrict__ top_w,
                               const int* __restrict__ chunkBase,
                               int* __restrict__ list, float* __restrict__ wlist,
                               int* __restrict__ inv) {
  __shared__ int lcnt[8];
  if (threadIdx.x < 8) lcnt[threadIdx.x] = 0;
  __syncthreads();
  int a = blockIdx.x * 256 + threadIdx.x;
  int e = top_e[a];
  int p = atomicAdd(&lcnt[e], 1);
  int pos = chunkBase[blockIdx.x * 8 + e] + p;
  list[pos] = a >> 1;
  wlist[pos] = top_w[a];
  inv[a] = pos;
}

// ---------------- GEMM: 128x128 tile, BK=32, 3-stage pipeline, counted vmcnt ----
// MODE 1: H = silu(X@W1+b1); logical [0,256) shared, [256,..) routed gather
// MODE 3: ybuf[pos] = w*(Hr@rW2+rb2)  (bf16 slot store, routed only)
// MODE 2: out = Hs@sW2+sb2 + y[slot0] + y[slot1]  (shared + fused combine)
//
// Pipeline: stage(kt+2) issued each iter; s_waitcnt vmcnt(4) waits ONLY for
// stage(kt+1) (issued a full iteration earlier), keeping kt+2's 4 loads in
// flight across the barrier. Each wave's own vmcnt(4) + s_barrier => all
// waves' buf[kt+1] writes complete before any wave reads it (T3/T4 recipe).

template<int MODE>
__global__ __launch_bounds__(256, 3)
void gemm_kernel(const __hip_bfloat16* __restrict__ Abase,
                 const __hip_bfloat16* __restrict__ Ws,
                 const __hip_bfloat16* __restrict__ Wr,
                 const float* __restrict__ bs,
                 const float* __restrict__ br,
                 __hip_bfloat16* __restrict__ Hout,
                 float* __restrict__ Oout,
                 __hip_bfloat16* __restrict__ Ybuf,
                 const int* __restrict__ counts,
                 const int* __restrict__ offs,
                 const int* __restrict__ tiles,
                 const int* __restrict__ list,
                 const float* __restrict__ wlist,
                 const int* __restrict__ inv) {
  constexpr int K    = (MODE == 1) ? 1024 : 512;
  constexpr int NN   = (MODE == 1) ? 512 : 1024;
  constexpr int LDBy = K * 2;
  constexpr int LNT  = (MODE == 1) ? 2 : 3;   // log2(n-tiles)
  constexpr int NT   = K / 32;

  __shared__ __hip_bfloat16 Abuf[3][128 * 32];
  __shared__ __hip_bfloat16 Bbuf[3][128 * 32];
  __shared__ int tokens[128];

  // bijective XCD-chunked swizzle (grid % 8 == 0)
  int l = ((blockIdx.x & 7) * (gridDim.x >> 3)) + (blockIdx.x >> 3);

  int e = 0, mt, nt;
  bool rb = false;
  if (MODE == 2) { mt = l >> 3; nt = l & 7; }
  else if (MODE == 1 && l < 256) { mt = l >> 2; nt = l & 3; }
  else {
    rb = true;
    int rq = (MODE == 1) ? (l - 256) : l;
    int rt = rq >> LNT; nt = rq & ((1 << LNT) - 1);
    if (rt >= tiles[8]) return;
    while (e < 7 && rt >= tiles[e + 1]) ++e;
    mt = rt - tiles[e];
  }
  int m0 = mt * 128;
  int cnt = 128;
  if (rb) {
    int ce = counts[e];
    cnt = (ce - m0 < 128) ? (ce - m0) : 128;
  }

  const __hip_bfloat16* W = rb ? (Wr + (size_t)e * NN * K) : Ws;
  const float* bias = rb ? (br + e * NN) : bs;

  int tid = threadIdx.x, wid = tid >> 6, lane = tid & 63;
  if (MODE == 1) {
    if (tid < 128)
      tokens[tid] = rb ? ((tid < cnt) ? list[offs[e] + m0 + tid] : 0) : (m0 + tid);
    __syncthreads();
  }
  int arow0 = rb ? (NTOK + offs[e] + m0) : m0;  // MODE 2/3

  // staging: LDS written linearly by gload_lds; global source pre-inverse-swizzled
  const char* aSrc[2];
  const char* bSrc[2];
  int ldsOff[2];
  #pragma unroll
  for (int c = 0; c < 2; c++) {
    ldsOff[c] = c * 4096 + wid * 1024;           // wave-uniform LDS base
    int s = ldsOff[c] + lane * 16;               // this lane's linear LDS byte
    int rho = s >> 6;                            // linear LDS row
    int klin = (s >> 4) & 3;
    int r = rho ^ ((rho >> 2) & 1);              // sigma^-1 row (involution)
    int k = klin ^ (r & 3);                      // sigma^-1 chunk
    long ar = (MODE == 1) ? (long)tokens[r] : (long)(arow0 + r);
    aSrc[c] = (const char*)Abase + (size_t)ar * LDBy + k * 16;
    bSrc[c] = (const char*)W + (size_t)(nt * 128 + r) * LDBy + k * 16;
  }

  int wm = wid >> 1, wn = wid & 1;
  int aoff[4], boff[4];
  #pragma unroll
  for (int m = 0; m < 4; m++) {
    int row = wm * 64 + m * 16 + (lane & 15);
    int rr = row ^ ((row >> 2) & 1);
    int kk = (lane >> 4) ^ (row & 3);
    aoff[m] = rr * 64 + kk * 16;
  }
  #pragma unroll
  for (int n = 0; n < 4; n++) {
    int row = wn * 64 + n * 16 + (lane & 15);
    int rr = row ^ ((row >> 2) & 1);
    int kk = (lane >> 4) ^ (row & 3);
    boff[n] = rr * 64 + kk * 16;
  }

  f32x4 zero = {0.f, 0.f, 0.f, 0.f};
  f32x4 acc[4][4];
  #pragma unroll
  for (int m = 0; m < 4; m++)
    #pragma unroll
    for (int n = 0; n < 4; n++) acc[m][n] = zero;

  auto stage = [&](int buf, int kt) {
    #pragma unroll
    for (int c = 0; c < 2; c++)
      gload16(aSrc[c] + (size_t)kt * 64, (char*)&Abuf[0][0] + buf * 8192 + ldsOff[c]);
    #pragma unroll
    for (int c = 0; c < 2; c++)
      gload16(bSrc[c] + (size_t)kt * 64, (char*)&Bbuf[0][0] + buf * 8192 + ldsOff[c]);
  };

  // prologue: stage tiles 0 and 1; wait only for tile 0 (oldest 4 of 8 in flight)
  stage(0, 0);
  stage(1, 1);
  asm volatile("s_waitcnt vmcnt(4)" ::: "memory");
  __builtin_amdgcn_s_barrier();
  __builtin_amdgcn_sched_barrier(0);

  int cur = 0;
  for (int kt = 0; kt < NT; ++kt) {
    const char* lA = (const char*)&Abuf[0][0] + cur * 8192;
    const char* lB = (const char*)&Bbuf[0][0] + cur * 8192;
    bf16x8 a[4], b[4];
    #pragma unroll
    for (int m = 0; m < 4; m++) a[m] = *(const bf16x8*)(lA + aoff[m]);
    #pragma unroll
    for (int n = 0; n < 4; n++) b[n] = *(const bf16x8*)(lB + boff[n]);
    #pragma unroll
    for (int m = 0; m < 4; m++)
      #pragma unroll
      for (int n = 0; n < 4; n++)
        acc[m][n] = __builtin_amdgcn_mfma_f32_16x16x32_bf16(a[m], b[n], acc[m][n], 0, 0, 0);
    if (kt + 2 < NT) {
      int sb = cur + 2; if (sb >= 3) sb -= 3;
      stage(sb, kt + 2);
      asm volatile("s_waitcnt vmcnt(4)" ::: "memory");   // stage(kt+1) done; kt+2 in flight
    } else {
      asm volatile("s_waitcnt vmcnt(0)" ::: "memory");   // tail: drain
    }
    __builtin_amdgcn_s_barrier();
    __builtin_amdgcn_sched_barrier(0);
    cur = (cur == 2) ? 0 : cur + 1;
  }

  int colBase = nt * 128 + wn * 64;
  if (MODE == 1) {
    size_t hrow0 = rb ? (size_t)(NTOK + offs[e] + m0) : (size_t)m0;
    #pragma unroll
    for (int m = 0; m < 4; m++) {
      #pragma unroll
      for (int r = 0; r < 4; r++) {
        int rl = wm * 64 + m * 16 + ((lane >> 4) << 2) + r;
        if (rl < cnt) {
          #pragma unroll
          for (int n = 0; n < 4; n++) {
            int col = colBase + n * 16 + (lane & 15);
            float v = acc[m][n][r] + bias[col];
            v = v / (1.f + __expf(-v));  // silu
            Hout[(hrow0 + rl) * HDIM + col] = __float2bfloat16(v);
          }
        }
      }
    }
  } else if (MODE == 2) {
    #pragma unroll
    for (int m = 0; m < 4; m++) {
      #pragma unroll
      for (int r = 0; r < 4; r++) {
        int rl = wm * 64 + m * 16 + ((lane >> 4) << 2) + r;
        int t = m0 + rl;
        int p0 = inv[t * 2], p1 = inv[t * 2 + 1];
        #pragma unroll
        for (int n = 0; n < 4; n++) {
          int col = colBase + n * 16 + (lane & 15);
          float v = acc[m][n][r] + bias[col]
                  + __bfloat162float(Ybuf[(size_t)p0 * DDIM + col])
                  + __bfloat162float(Ybuf[(size_t)p1 * DDIM + col]);
          Oout[(size_t)t * DDIM + col] = v;
        }
      }
    }
  } else {
    #pragma unroll
    for (int m = 0; m < 4; m++) {
      #pragma unroll
      for (int r = 0; r < 4; r++) {
        int rl = wm * 64 + m * 16 + ((lane >> 4) << 2) + r;
        if (rl < cnt) {
          int pos = offs[e] + m0 + rl;
          float w = wlist[pos];
          #pragma unroll
          for (int n = 0; n < 4; n++) {
            int col = colBase + n * 16 + (lane & 15);
            Ybuf[(size_t)pos * DDIM + col] = __float2bfloat16(w * (acc[m][n][r] + bias[col]));
          }
        }
      }
    }
  }
}

// ---------------- launch ----------------

extern "C" void kernel_launch(void* const* d_in, const int* in_sizes, int n_in,
                              void* d_out, int out_size, void* d_ws, size_t ws_size,
                              hipStream_t stream) {
  const float* X   = (const float*)d_in[0];
  const float* rWt = (const float*)d_in[1];
  const float* eb  = (const float*)d_in[2];
  const float* sW1 = (const float*)d_in[3];
  const float* sb1 = (const float*)d_in[4];
  const float* sW2 = (const float*)d_in[5];
  const float* sb2 = (const float*)d_in[6];
  const float* rW1 = (const float*)d_in[7];
  const float* rb1 = (const float*)d_in[8];
  const float* rW2 = (const float*)d_in[9];
  const float* rb2 = (const float*)d_in[10];
  float* out = (float*)d_out;

  char* ws = (char*)d_ws;
  size_t off = 0;
  auto alloc = [&](size_t bytes) {
    char* p = ws + off;
    off += (bytes + 255) & ~(size_t)255;
    return p;
  };
  // Region 0 (32 MB): {Xb, sW1t, rW1t} live through gemm<1>; aliased afterward
  // by Ybuf (16384 x 1024 bf16), written by gemm<3>, read by gemm<2> epilogue.
  char* region0 = alloc((size_t)16384 * DDIM * 2);
  __hip_bfloat16* Xb   = (__hip_bfloat16*)region0;
  __hip_bfloat16* sW1t = (__hip_bfloat16*)(region0 + (size_t)NTOK * DDIM * 2);
  __hip_bfloat16* rW1t = (__hip_bfloat16*)(region0 + (size_t)NTOK * DDIM * 2
                                                   + (size_t)HDIM * DDIM * 2);
  __hip_bfloat16* Ybuf = (__hip_bfloat16*)region0;

  __hip_bfloat16* sW2t = (__hip_bfloat16*)alloc((size_t)DDIM * HDIM * 2);
  __hip_bfloat16* rW2t = (__hip_bfloat16*)alloc((size_t)8 * DDIM * HDIM * 2);
  __hip_bfloat16* Hbuf = (__hip_bfloat16*)alloc((size_t)(NTOK + 2 * NTOK) * HDIM * 2);
  alloc(131072);  // pad: partial-tile A reads may run past Hbuf end
  int* counts    = (int*)alloc(64);
  int* offsA     = (int*)alloc(64);
  int* tiles     = (int*)alloc(64);
  int* top_e     = (int*)alloc((size_t)NTOK * 2 * 4);
  float* top_w   = (float*)alloc((size_t)NTOK * 2 * 4);
  int* list      = (int*)alloc((size_t)NTOK * 2 * 4);
  float* wlist   = (float*)alloc((size_t)NTOK * 2 * 4);
  int* inv       = (int*)alloc((size_t)NTOK * 2 * 4);
  int* chunkBase = (int*)alloc(64 * 8 * 4);

  convert_route_kernel<<<2048, 256, 0, stream>>>(X, rWt, eb, Xb, top_e, top_w);
  convert_w_kernel<<<dim3(16, 32, 9), 256, 0, stream>>>(sW1, rW1, sW1t, rW1t, 1024, 512);
  convert_w_kernel<<<dim3(32, 16, 9), 256, 0, stream>>>(sW2, rW2, sW2t, rW2t, 512, 1024);
  hist_scan_kernel<<<1, 512, 0, stream>>>(top_e, chunkBase, counts, offsA, tiles);
  scatter_kernel<<<64, 256, 0, stream>>>(top_e, top_w, chunkBase, list, wlist, inv);
  // grids all % 8 == 0 for the XCD swizzle
  gemm_kernel<1><<<256 + 4 * 136, 256, 0, stream>>>(Xb, sW1t, rW1t, sb1, rb1, Hbuf, out,
                                                    nullptr, counts, offsA, tiles, list, wlist, inv);
  gemm_kernel<3><<<8 * 136, 256, 0, stream>>>(Hbuf, sW2t, rW2t, sb2, rb2, nullptr, out,
                                              Ybuf, counts, offsA, tiles, list, wlist, inv);
  gemm_kernel<2><<<64 * 8, 256, 0, stream>>>(Hbuf, sW2t, rW2t, sb2, rb2, nullptr, out,
                                             Ybuf, counts, offsA, tiles, list, wlist, inv);
}